// Round 6
// baseline (213.663 us; speedup 1.0000x reference)
//
#include <hip/hip_runtime.h>
#include <hip/hip_fp16.h>

#define NF 14
#define DIMOUT 16
#define BSH 9         // 512 nodes per bucket
#define NPBKT 512     // nodes per bucket
#define NBKT 256      // allocated buckets (used: ceil(N/512) = 196)
#define C1 4096       // edges per scatter1 block

// ---- detect whether edge_index buffer is int64 (odd int32 words all zero) ----
__global__ void k_detect(const int* __restrict__ e32, int* __restrict__ flag) {
    int is64 = 1;
    for (int i = 1; i < 64; i += 2) {
        if (e32[i] != 0) { is64 = 0; break; }
    }
    *flag = is64;
}

// ---- bucket-level histogram of dst ----
__global__ __launch_bounds__(256) void k_bhist(const void* __restrict__ edges,
                                               const int* __restrict__ flag,
                                               int* __restrict__ bhist, int E) {
    __shared__ int h[NBKT];
    int t = threadIdx.x;
    h[t] = 0;
    __syncthreads();
    const bool is64 = (*flag != 0);
    const long long* e64 = (const long long*)edges;
    const int* e32 = (const int*)edges;
    int stride = gridDim.x * blockDim.x;
    for (int i = blockIdx.x * blockDim.x + t; i < E; i += stride) {
        int dst = is64 ? (int)e64[(size_t)E + i] : e32[(size_t)E + i];
        atomicAdd(&h[dst >> BSH], 1);
    }
    __syncthreads();
    if (h[t]) atomicAdd(&bhist[t], h[t]);
}

// ---- scan bucket histogram -> region bases + live cursors ----
__global__ __launch_bounds__(NBKT) void k_bscan(const int* __restrict__ bhist,
                                                int* __restrict__ gregion,
                                                int* __restrict__ gcur, int E) {
    __shared__ int sm[NBKT];
    int t = threadIdx.x;
    int v = bhist[t];
    sm[t] = v;
    __syncthreads();
    for (int d = 1; d < NBKT; d <<= 1) {
        int u = (t >= d) ? sm[t - d] : 0;
        __syncthreads();
        sm[t] += u;
        __syncthreads();
    }
    int ex = sm[t] - v;
    gregion[t] = ex;
    gcur[t] = ex;
    if (t == NBKT - 1) gregion[NBKT] = sm[t];  // == E
}

// ---- pass 1: block-local LDS counting sort by bucket, burst-copy out ----
// packed entry: (dst & 511) << 17 | src   (src < 131072)
__global__ __launch_bounds__(256) void k_scatter1(const void* __restrict__ edges,
                                                  const int* __restrict__ flag,
                                                  int* __restrict__ gcur,
                                                  unsigned int* __restrict__ pairs, int E) {
    __shared__ unsigned int raw[C1];
    __shared__ unsigned int srt[C1];
    __shared__ unsigned short bkt[C1];
    __shared__ unsigned short sbk[C1];
    __shared__ int hist[NBKT], scn[NBKT], gb[NBKT], cur[NBKT];
    const bool is64 = (*flag != 0);
    const long long* e64 = (const long long*)edges;
    const int* e32 = (const int*)edges;
    const int t = threadIdx.x;
    const int base = blockIdx.x * C1;
    const int cnt = min(C1, E - base);
    hist[t] = 0;
    cur[t] = 0;
    __syncthreads();
    for (int j = t; j < cnt; j += 256) {
        int i = base + j;
        int src, dst;
        if (is64) {
            src = (int)e64[i];
            dst = (int)e64[(size_t)E + i];
        } else {
            src = e32[i];
            dst = e32[(size_t)E + i];
        }
        int b = dst >> BSH;
        raw[j] = (unsigned int)src | ((unsigned int)(dst & (NPBKT - 1)) << 17);
        bkt[j] = (unsigned short)b;
        atomicAdd(&hist[b], 1);
    }
    __syncthreads();
    int v = hist[t];
    scn[t] = v;
    __syncthreads();
    for (int d = 1; d < NBKT; d <<= 1) {
        int u = (t >= d) ? scn[t - d] : 0;
        __syncthreads();
        scn[t] += u;
        __syncthreads();
    }
    int ex = scn[t] - v;
    gb[t] = v ? atomicAdd(&gcur[t], v) : 0;  // reserve run in bucket t's region
    __syncthreads();
    scn[t] = ex;
    __syncthreads();
    for (int j = t; j < cnt; j += 256) {
        int b = bkt[j];
        int r = atomicAdd(&cur[b], 1);
        int pos = scn[b] + r;
        srt[pos] = raw[j];
        sbk[pos] = (unsigned short)b;
    }
    __syncthreads();
    for (int j = t; j < cnt; j += 256) {
        int b = sbk[j];
        pairs[gb[b] + (j - scn[b])] = srt[j];  // sequential within runs
    }
}

// ---- pass 2: per-bucket LDS counting sort -> node CSR + offsets + dinv ----
__global__ __launch_bounds__(256) void k_sort2(const unsigned int* __restrict__ pairs,
                                               const int* __restrict__ gregion,
                                               int* __restrict__ srcs,
                                               int* __restrict__ offsets,
                                               float* __restrict__ dinv, int N, int E) {
    __shared__ int cnt[NPBKT], off[NPBKT], cur[NPBKT];
    __shared__ int sm[256];
    const int b = blockIdx.x, t = threadIdx.x;
    const int e0 = gregion[b], e1 = gregion[b + 1];
    cnt[2 * t] = 0;
    cnt[2 * t + 1] = 0;
    cur[2 * t] = 0;
    cur[2 * t + 1] = 0;
    __syncthreads();
    for (int e = e0 + t; e < e1; e += 256) atomicAdd(&cnt[pairs[e] >> 17], 1);
    __syncthreads();
    int h0 = cnt[2 * t], h1 = cnt[2 * t + 1];
    int s = h0 + h1;
    sm[t] = s;
    __syncthreads();
    for (int d = 1; d < 256; d <<= 1) {
        int u = (t >= d) ? sm[t - d] : 0;
        __syncthreads();
        sm[t] += u;
        __syncthreads();
    }
    int ex = sm[t] - s;
    off[2 * t] = ex;
    off[2 * t + 1] = ex + h0;
    __syncthreads();
    for (int l = t; l < NPBKT; l += 256) {
        int n = (b << BSH) + l;
        if (n < N) {
            offsets[n] = e0 + off[l];
            dinv[n] = rsqrtf((float)(cnt[l] + 1));
        }
    }
    if (b == 0 && t == 0) offsets[N] = E;
    for (int e = e0 + t; e < e1; e += 256) {
        unsigned int p = pairs[e];
        int l = p >> 17;
        int r = atomicAdd(&cur[l], 1);
        srcs[e0 + off[l] + r] = (int)(p & 0x1FFFFu);  // L2-local scatter (64KB window)
    }
}

// ---- prep: u0[n] = fp16( dinv[n] * (x[n] @ W^T) ), 16 halves/row ----
// (S commutes with W: propagate y = x W^T instead of x, apply W only once here)
__global__ __launch_bounds__(256) void k_prep(const float* __restrict__ x,
                                              const float* __restrict__ dinv,
                                              const float* __restrict__ Wg,
                                              __half2* __restrict__ u0, int N) {
    __shared__ float Wl[DIMOUT * NF];
    int t = threadIdx.x;
    if (t < DIMOUT * NF) Wl[t] = Wg[t];
    __syncthreads();
    int n = blockIdx.x * 256 + t;
    if (n >= N) return;
    float xr[NF];
#pragma unroll
    for (int f = 0; f < NF; ++f) xr[f] = x[(size_t)n * NF + f];
    float dn = dinv[n];
#pragma unroll
    for (int q = 0; q < 8; ++q) {
        float r0 = 0.f, r1 = 0.f;
#pragma unroll
        for (int f = 0; f < NF; ++f) {
            r0 += xr[f] * Wl[(2 * q) * NF + f];
            r1 += xr[f] * Wl[(2 * q + 1) * NF + f];
        }
        u0[(size_t)n * 8 + q] = __halves2half2(__float2half(dn * r0), __float2half(dn * r1));
    }
}

// ---- hop: wave per node, 8-way edge-parallel, fp16 16-dim rows ----
// FINAL=0: u1 = fp16( dn^2 * (sum_in u + u_self) )
// FINAL=1: out = dn * (sum_in u + u_self) + bias   (fp32)
template <int FINAL>
__global__ __launch_bounds__(256) void k_hop(const __half2* __restrict__ u,
                                             const int* __restrict__ srcs,
                                             const int* __restrict__ offsets,
                                             const float* __restrict__ dinv,
                                             const float* __restrict__ bias,
                                             __half2* __restrict__ outh,
                                             float* __restrict__ outf, int N) {
    const int lane = threadIdx.x & 63;
    const int fp = lane & 7;   // feature-pair lane (half2 index)
    const int ep = lane >> 3;  // 0..7 edge-parallel subgroup
    const int n = blockIdx.x * 4 + (threadIdx.x >> 6);
    if (n >= N) return;  // wave-uniform

    const int beg = offsets[n];
    const int end = offsets[n + 1];
    float ax = 0.f, ay = 0.f;
    int e = beg + ep;
    // 4-deep independent chains: one iteration covers 32 edges per wave
    for (; e + 24 < end; e += 32) {
        int s0 = __builtin_nontemporal_load(srcs + e);
        int s1 = __builtin_nontemporal_load(srcs + e + 8);
        int s2 = __builtin_nontemporal_load(srcs + e + 16);
        int s3 = __builtin_nontemporal_load(srcs + e + 24);
        float2 f0 = __half22float2(u[s0 * 8 + fp]);
        float2 f1 = __half22float2(u[s1 * 8 + fp]);
        float2 f2 = __half22float2(u[s2 * 8 + fp]);
        float2 f3 = __half22float2(u[s3 * 8 + fp]);
        ax += (f0.x + f1.x) + (f2.x + f3.x);
        ay += (f0.y + f1.y) + (f2.y + f3.y);
    }
    for (; e < end; e += 8) {
        int s0 = __builtin_nontemporal_load(srcs + e);
        float2 f0 = __half22float2(u[s0 * 8 + fp]);
        ax += f0.x;
        ay += f0.y;
    }
    ax += __shfl_xor(ax, 8);
    ay += __shfl_xor(ay, 8);
    ax += __shfl_xor(ax, 16);
    ay += __shfl_xor(ay, 16);
    ax += __shfl_xor(ax, 32);
    ay += __shfl_xor(ay, 32);
    float2 fs = __half22float2(u[n * 8 + fp]);  // self loop
    ax += fs.x;
    ay += fs.y;
    float dn = dinv[n];
    if (!FINAL) {
        if (ep == 0) {
            float s = dn * dn;
            outh[(size_t)n * 8 + fp] =
                __halves2half2(__float2half(s * ax), __float2half(s * ay));
        }
    } else {
        if (ep == 0) {
            float2 o;
            o.x = dn * ax + bias[2 * fp];
            o.y = dn * ay + bias[2 * fp + 1];
            *(float2*)(outf + (size_t)n * DIMOUT + 2 * fp) = o;
        }
    }
}

extern "C" void kernel_launch(void* const* d_in, const int* in_sizes, int n_in,
                              void* d_out, int out_size, void* d_ws, size_t ws_size,
                              hipStream_t stream) {
    const float* x = (const float*)d_in[0];
    const void* edges = d_in[1];
    const float* W = (const float*)d_in[2];
    const float* b = (const float*)d_in[3];
    float* out = (float*)d_out;

    const int N = in_sizes[0] / NF;  // 100000
    const int E = in_sizes[1] / 2;   // 3200000

    char* ws = (char*)d_ws;
    size_t o = 0;
    auto alloc = [&](size_t bytes) -> void* {
        o = (o + 255) & ~(size_t)255;
        void* p = ws + o;
        o += bytes;
        return p;
    };
    int* flag = (int*)alloc(16);
    int* bhist = (int*)alloc((size_t)NBKT * sizeof(int));
    int* gregion = (int*)alloc(((size_t)NBKT + 1) * sizeof(int));
    int* gcur = (int*)alloc((size_t)NBKT * sizeof(int));
    unsigned int* pairs = (unsigned int*)alloc((size_t)E * sizeof(unsigned int));
    int* srcs = (int*)alloc((size_t)E * sizeof(int));
    int* offsets = (int*)alloc(((size_t)N + 1) * sizeof(int));
    float* dinv = (float*)alloc((size_t)N * sizeof(float));
    __half2* u0 = (__half2*)alloc((size_t)N * 8 * sizeof(__half2));
    __half2* u1 = (__half2*)alloc((size_t)N * 8 * sizeof(__half2));
    (void)ws_size;
    (void)n_in;
    (void)out_size;

    hipMemsetAsync(bhist, 0, (size_t)NBKT * sizeof(int), stream);
    k_detect<<<1, 1, 0, stream>>>((const int*)edges, flag);
    k_bhist<<<512, 256, 0, stream>>>(edges, flag, bhist, E);
    k_bscan<<<1, NBKT, 0, stream>>>(bhist, gregion, gcur, E);
    k_scatter1<<<(E + C1 - 1) / C1, 256, 0, stream>>>(edges, flag, gcur, pairs, E);
    k_sort2<<<(N + NPBKT - 1) >> BSH, 256, 0, stream>>>(pairs, gregion, srcs, offsets, dinv, N, E);
    k_prep<<<(N + 255) / 256, 256, 0, stream>>>(x, dinv, W, u0, N);

    int hopgrid = (N + 3) / 4;
    k_hop<0><<<hopgrid, 256, 0, stream>>>(u0, srcs, offsets, dinv, nullptr, u1, nullptr, N);
    k_hop<1><<<hopgrid, 256, 0, stream>>>(u1, srcs, offsets, dinv, b, nullptr, out, N);
}

// Round 7
// 167.689 us; speedup vs baseline: 1.2742x; 1.2742x over previous
//
#include <hip/hip_runtime.h>
#include <hip/hip_fp16.h>

#define NF 14
#define DIMOUT 16
#define BSH 9              // 512 nodes per bucket
#define NPBKT 512          // nodes per bucket
#define NBKT 256           // allocated buckets (used: ceil(N/512) = 196)
#define C1 4096            // edges per scatter block
#define PADCAP (NPBKT * 16)  // worst-case per-bucket extra entries (self + pad-to-16)

// ---- detect whether edge_index buffer is int64 (odd int32 words all zero) ----
__global__ void k_detect(const int* __restrict__ e32, int* __restrict__ flag) {
    int is64 = 1;
    for (int i = 1; i < 64; i += 2) {
        if (e32[i] != 0) { is64 = 0; break; }
    }
    *flag = is64;
}

// ---- per-block local bucket histogram (no global atomics) ----
__global__ __launch_bounds__(256) void k_lhist(const void* __restrict__ edges,
                                               const int* __restrict__ flag,
                                               int* __restrict__ lhistT, int E, int NBLK) {
    __shared__ int h[NBKT];
    const int t = threadIdx.x;
    h[t] = 0;
    __syncthreads();
    const bool is64 = (*flag != 0);
    const long long* e64 = (const long long*)edges;
    const int* e32 = (const int*)edges;
    const int base = blockIdx.x * C1;
    const int cnt = min(C1, E - base);
    for (int j = t; j < cnt; j += 256) {
        int i = base + j;
        int dst = is64 ? (int)e64[(size_t)E + i] : e32[(size_t)E + i];
        atomicAdd(&h[dst >> BSH], 1);  // LDS only
    }
    __syncthreads();
    lhistT[(size_t)t * NBLK + blockIdx.x] = h[t];  // transposed: [bucket][block]
}

// ---- per-bucket scan over blocks: lbase[bucket][block] + bucket totals ----
__global__ __launch_bounds__(256) void k_cscan(const int* __restrict__ lhistT,
                                               int* __restrict__ lbase,
                                               int* __restrict__ btot, int NBLK) {
    const int b = blockIdx.x;
    const int t = threadIdx.x;
    const int IPT = (NBLK + 255) / 256;  // <=8 for E<=8M
    int v[8];
    int s = 0;
    for (int k = 0; k < IPT; ++k) {
        int j = t * IPT + k;
        int x = (j < NBLK) ? lhistT[(size_t)b * NBLK + j] : 0;
        v[k] = x;
        s += x;
    }
    __shared__ int sm[256];
    sm[t] = s;
    __syncthreads();
    for (int d = 1; d < 256; d <<= 1) {
        int u = (t >= d) ? sm[t - d] : 0;
        __syncthreads();
        sm[t] += u;
        __syncthreads();
    }
    int run = sm[t] - s;  // exclusive prefix
    for (int k = 0; k < IPT; ++k) {
        int j = t * IPT + k;
        if (j < NBLK) {
            lbase[(size_t)b * NBLK + j] = run;
            run += v[k];
        }
    }
    if (t == 255) btot[b] = sm[255];
}

// ---- exclusive scan of bucket totals -> bucket regions ----
__global__ __launch_bounds__(NBKT) void k_gscan(const int* __restrict__ btot,
                                                int* __restrict__ gregion) {
    __shared__ int sm[NBKT];
    int t = threadIdx.x;
    int v = btot[t];
    sm[t] = v;
    __syncthreads();
    for (int d = 1; d < NBKT; d <<= 1) {
        int u = (t >= d) ? sm[t - d] : 0;
        __syncthreads();
        sm[t] += u;
        __syncthreads();
    }
    gregion[t] = sm[t] - v;
    if (t == NBKT - 1) gregion[NBKT] = sm[t];  // == E
}

// ---- scatter: block-local LDS counting sort, runs written at exact bases ----
// packed entry: (dst & 511) << 17 | src   (src < 131072)
__global__ __launch_bounds__(256) void k_scatter(const void* __restrict__ edges,
                                                 const int* __restrict__ flag,
                                                 const int* __restrict__ gregion,
                                                 const int* __restrict__ lbase,
                                                 unsigned int* __restrict__ pairs,
                                                 int E, int NBLK) {
    __shared__ unsigned int raw[C1];
    __shared__ unsigned int srt[C1];
    __shared__ unsigned short bkt[C1];
    __shared__ unsigned short sbk[C1];
    __shared__ int hist[NBKT], scn[NBKT], gb[NBKT], cur[NBKT];
    const bool is64 = (*flag != 0);
    const long long* e64 = (const long long*)edges;
    const int* e32 = (const int*)edges;
    const int t = threadIdx.x;
    const int base = blockIdx.x * C1;
    const int cnt = min(C1, E - base);
    hist[t] = 0;
    cur[t] = 0;
    __syncthreads();
    for (int j = t; j < cnt; j += 256) {
        int i = base + j;
        int src, dst;
        if (is64) {
            src = (int)e64[i];
            dst = (int)e64[(size_t)E + i];
        } else {
            src = e32[i];
            dst = e32[(size_t)E + i];
        }
        int b = dst >> BSH;
        raw[j] = (unsigned int)src | ((unsigned int)(dst & (NPBKT - 1)) << 17);
        bkt[j] = (unsigned short)b;
        atomicAdd(&hist[b], 1);  // LDS only
    }
    __syncthreads();
    int v = hist[t];
    scn[t] = v;
    __syncthreads();
    for (int d = 1; d < NBKT; d <<= 1) {
        int u = (t >= d) ? scn[t - d] : 0;
        __syncthreads();
        scn[t] += u;
        __syncthreads();
    }
    int ex = scn[t] - v;
    gb[t] = gregion[t] + lbase[(size_t)t * NBLK + blockIdx.x];  // deterministic base
    __syncthreads();
    scn[t] = ex;
    __syncthreads();
    for (int j = t; j < cnt; j += 256) {
        int b = bkt[j];
        int r = atomicAdd(&cur[b], 1);  // LDS only
        int pos = scn[b] + r;
        srt[pos] = raw[j];
        sbk[pos] = (unsigned short)b;
    }
    __syncthreads();
    for (int j = t; j < cnt; j += 256) {
        int b = sbk[j];
        pairs[gb[b] + (j - scn[b])] = srt[j];  // sequential within runs
    }
}

// ---- per-bucket counting sort -> padded CSR (self-loop included, pad to 16) ----
__global__ __launch_bounds__(256) void k_sort2(const unsigned int* __restrict__ pairs,
                                               const int* __restrict__ gregion,
                                               int* __restrict__ srcs,
                                               int2* __restrict__ off2,
                                               float* __restrict__ dinv, int N) {
    __shared__ int cnt[NPBKT], poff[NPBKT], cur[NPBKT];
    __shared__ int sm[256];
    const int b = blockIdx.x, t = threadIdx.x;
    const int e0 = gregion[b], e1 = gregion[b + 1];
    const int pbase = e0 + b * PADCAP;
    cnt[2 * t] = 0;
    cnt[2 * t + 1] = 0;
    __syncthreads();
    for (int e = e0 + t; e < e1; e += 256) atomicAdd(&cnt[pairs[e] >> 17], 1);
    __syncthreads();
    int c0 = cnt[2 * t], c1 = cnt[2 * t + 1];
    int p0 = (c0 + 16) & ~15;  // round_up(c0 + 1, 16): self-loop + pad
    int p1 = (c1 + 16) & ~15;
    int s = p0 + p1;
    sm[t] = s;
    __syncthreads();
    for (int d = 1; d < 256; d <<= 1) {
        int u = (t >= d) ? sm[t - d] : 0;
        __syncthreads();
        sm[t] += u;
        __syncthreads();
    }
    int ex = sm[t] - s;
    poff[2 * t] = ex;
    poff[2 * t + 1] = ex + p0;
    cur[2 * t] = 1;      // slot 0 = self edge
    cur[2 * t + 1] = 1;
    __syncthreads();
    for (int l = t; l < NPBKT; l += 256) {
        int n = (b << BSH) + l;
        if (n < N) {
            int c = cnt[l];
            int p = (c + 16) & ~15;
            int ob = pbase + poff[l];
            off2[n] = make_int2(ob, ob + p);
            dinv[n] = rsqrtf((float)(c + 1));
            srcs[ob] = n;                                  // self loop
            for (int k = c + 1; k < p; ++k) srcs[ob + k] = N;  // sentinel pad
        }
    }
    __syncthreads();
    for (int e = e0 + t; e < e1; e += 256) {
        unsigned int p = pairs[e];
        int l = p >> 17;
        int r = atomicAdd(&cur[l], 1);  // LDS only
        srcs[pbase + poff[l] + r] = (int)(p & 0x1FFFFu);
    }
}

// ---- prep: u0[n] = fp16( dinv[n] * (x[n] @ W^T) ), 16 halves/row ----
__global__ __launch_bounds__(256) void k_prep(const float* __restrict__ x,
                                              const float* __restrict__ dinv,
                                              const float* __restrict__ Wg,
                                              __half2* __restrict__ u0, int N) {
    __shared__ float Wl[DIMOUT * NF];
    int t = threadIdx.x;
    if (t < DIMOUT * NF) Wl[t] = Wg[t];
    __syncthreads();
    int n = blockIdx.x * 256 + t;
    if (n >= N) return;
    float xr[NF];
#pragma unroll
    for (int f = 0; f < NF; ++f) xr[f] = x[(size_t)n * NF + f];
    float dn = dinv[n];
#pragma unroll
    for (int q = 0; q < 8; ++q) {
        float r0 = 0.f, r1 = 0.f;
#pragma unroll
        for (int f = 0; f < NF; ++f) {
            r0 += xr[f] * Wl[(2 * q) * NF + f];
            r1 += xr[f] * Wl[(2 * q + 1) * NF + f];
        }
        u0[(size_t)n * 8 + q] = __floats2half2_rn(dn * r0, dn * r1);
    }
}

// ---- hop: wave per node, 16-way edge-parallel, 8B lanes, padded lists ----
// FINAL=0: u1 = fp16( dn^2 * acc )   FINAL=1: out = dn * acc + bias (fp32)
template <int FINAL>
__global__ __launch_bounds__(256) void k_hop(const uint2* __restrict__ u8,
                                             const int* __restrict__ srcs,
                                             const int2* __restrict__ off2,
                                             const float* __restrict__ dinv,
                                             const float* __restrict__ bias,
                                             uint2* __restrict__ outh,
                                             float* __restrict__ outf, int N) {
    const int lane = threadIdx.x & 63;
    const int fp = lane & 3;   // quarter-row lane (8B = 4 halves)
    const int ep = lane >> 2;  // 0..15 edge-parallel subgroup
    const int n = blockIdx.x * 4 + (threadIdx.x >> 6);
    if (n >= N) return;  // wave-uniform
    const int2 oo = off2[n];
    const int beg = oo.x, end = oo.y;  // (end-beg) % 16 == 0, >= 16
    float ax = 0.f, ay = 0.f, az = 0.f, aw = 0.f;
    int e = beg + ep;
    for (; e + 16 < end; e += 32) {  // 2-deep: 32 edges per wave-iteration
        int s0 = srcs[e];
        int s1 = srcs[e + 16];
        uint2 q0 = u8[(size_t)s0 * 4 + fp];
        uint2 q1 = u8[(size_t)s1 * 4 + fp];
        float2 a0 = __half22float2(*(__half2*)&q0.x);
        float2 b0 = __half22float2(*(__half2*)&q0.y);
        float2 a1 = __half22float2(*(__half2*)&q1.x);
        float2 b1 = __half22float2(*(__half2*)&q1.y);
        ax += a0.x + a1.x;
        ay += a0.y + a1.y;
        az += b0.x + b1.x;
        aw += b0.y + b1.y;
    }
    if (e < end) {  // at most one leftover 16-chunk, fully parallel
        int s0 = srcs[e];
        uint2 q0 = u8[(size_t)s0 * 4 + fp];
        float2 a0 = __half22float2(*(__half2*)&q0.x);
        float2 b0 = __half22float2(*(__half2*)&q0.y);
        ax += a0.x;
        ay += a0.y;
        az += b0.x;
        aw += b0.y;
    }
#pragma unroll
    for (int d = 4; d <= 32; d <<= 1) {
        ax += __shfl_xor(ax, d);
        ay += __shfl_xor(ay, d);
        az += __shfl_xor(az, d);
        aw += __shfl_xor(aw, d);
    }
    if (ep != 0) return;
    float dn = dinv[n];
    if (!FINAL) {
        float s = dn * dn;
        __half2 h0 = __floats2half2_rn(s * ax, s * ay);
        __half2 h1 = __floats2half2_rn(s * az, s * aw);
        uint2 q;
        q.x = *(unsigned*)&h0;
        q.y = *(unsigned*)&h1;
        outh[(size_t)n * 4 + fp] = q;
    } else {
        float4 o;
        o.x = dn * ax + bias[4 * fp];
        o.y = dn * ay + bias[4 * fp + 1];
        o.z = dn * az + bias[4 * fp + 2];
        o.w = dn * aw + bias[4 * fp + 3];
        *(float4*)(outf + (size_t)n * DIMOUT + 4 * fp) = o;
    }
}

extern "C" void kernel_launch(void* const* d_in, const int* in_sizes, int n_in,
                              void* d_out, int out_size, void* d_ws, size_t ws_size,
                              hipStream_t stream) {
    const float* x = (const float*)d_in[0];
    const void* edges = d_in[1];
    const float* W = (const float*)d_in[2];
    const float* b = (const float*)d_in[3];
    float* out = (float*)d_out;

    const int N = in_sizes[0] / NF;  // 100000
    const int E = in_sizes[1] / 2;   // 3200000
    const int NBLK = (E + C1 - 1) / C1;
    const int NUSED = (N + NPBKT - 1) >> BSH;

    char* ws = (char*)d_ws;
    size_t o = 0;
    auto alloc = [&](size_t bytes) -> void* {
        o = (o + 255) & ~(size_t)255;
        void* p = ws + o;
        o += bytes;
        return p;
    };
    int* flag = (int*)alloc(16);
    int* lhistT = (int*)alloc((size_t)NBKT * NBLK * sizeof(int));
    int* lbase = (int*)alloc((size_t)NBKT * NBLK * sizeof(int));
    int* btot = (int*)alloc((size_t)NBKT * sizeof(int));
    int* gregion = (int*)alloc(((size_t)NBKT + 1) * sizeof(int));
    unsigned int* pairs = (unsigned int*)alloc((size_t)E * sizeof(unsigned int));
    int* srcs = (int*)alloc(((size_t)E + (size_t)(NUSED + 1) * PADCAP) * sizeof(int));
    int2* off2 = (int2*)alloc((size_t)N * sizeof(int2));
    float* dinv = (float*)alloc((size_t)N * sizeof(float));
    __half* u0 = (__half*)alloc((size_t)(N + 1) * 16 * sizeof(__half));
    __half* u1 = (__half*)alloc((size_t)(N + 1) * 16 * sizeof(__half));
    (void)ws_size;
    (void)n_in;
    (void)out_size;

    k_detect<<<1, 1, 0, stream>>>((const int*)edges, flag);
    k_lhist<<<NBLK, 256, 0, stream>>>(edges, flag, lhistT, E, NBLK);
    k_cscan<<<NBKT, 256, 0, stream>>>(lhistT, lbase, btot, NBLK);
    k_gscan<<<1, NBKT, 0, stream>>>(btot, gregion);
    k_scatter<<<NBLK, 256, 0, stream>>>(edges, flag, gregion, lbase, pairs, E, NBLK);
    k_sort2<<<NUSED, 256, 0, stream>>>(pairs, gregion, srcs, off2, dinv, N);
    // zero the sentinel rows (src = N points here)
    hipMemsetAsync(u0 + (size_t)N * 16, 0, 16 * sizeof(__half), stream);
    hipMemsetAsync(u1 + (size_t)N * 16, 0, 16 * sizeof(__half), stream);
    k_prep<<<(N + 255) / 256, 256, 0, stream>>>(x, dinv, W, (__half2*)u0, N);

    int hopgrid = (N + 3) / 4;
    k_hop<0><<<hopgrid, 256, 0, stream>>>((const uint2*)u0, srcs, off2, dinv, nullptr,
                                          (uint2*)u1, nullptr, N);
    k_hop<1><<<hopgrid, 256, 0, stream>>>((const uint2*)u1, srcs, off2, dinv, b,
                                          nullptr, out, N);
}

// Round 8
// 167.053 us; speedup vs baseline: 1.2790x; 1.0038x over previous
//
#include <hip/hip_runtime.h>
#include <hip/hip_fp16.h>

#define NF 14
#define DIMOUT 16
#define BSH 9        // 512 nodes per bucket
#define NPBKT 512
#define NBKT 256     // bucket count (used: ceil(N/512) = 196)
#define C1 4096      // edges per block in bucket passes
#define GSUB 8       // subchunks per bucket in node-level passes

// int64 edge buffer <=> odd 32-bit words (high halves) all zero (ids < 2^31)
__device__ __forceinline__ bool detect64(const int* e32) {
    bool is64 = true;
#pragma unroll
    for (int i = 1; i < 64; i += 2) is64 &= (e32[i] == 0);
    return is64;
}

// ---- per-block bucket histogram (transposed write) ----
__global__ __launch_bounds__(256) void k_lhist(const void* __restrict__ edges,
                                               int* __restrict__ lhistT, int E, int NBLK) {
    __shared__ int h[NBKT];
    const int t = threadIdx.x;
    h[t] = 0;
    __syncthreads();
    const int* e32 = (const int*)edges;
    const long long* e64 = (const long long*)edges;
    const bool is64 = detect64(e32);
    const int base = blockIdx.x * C1;
    const int cnt = min(C1, E - base);
    for (int j = t; j < cnt; j += 256) {
        int i = base + j;
        int dst = is64 ? (int)e64[(size_t)E + i] : e32[(size_t)E + i];
        atomicAdd(&h[dst >> BSH], 1);
    }
    __syncthreads();
    lhistT[(size_t)t * NBLK + blockIdx.x] = h[t];
}

// ---- per-bucket scan over blocks ----
__global__ __launch_bounds__(256) void k_cscan(const int* __restrict__ lhistT,
                                               int* __restrict__ lbase,
                                               int* __restrict__ btot, int NBLK) {
    const int b = blockIdx.x;
    const int t = threadIdx.x;
    const int IPT = (NBLK + 255) / 256;
    int v[8];
    int s = 0;
    for (int k = 0; k < IPT; ++k) {
        int j = t * IPT + k;
        int x = (j < NBLK) ? lhistT[(size_t)b * NBLK + j] : 0;
        v[k] = x;
        s += x;
    }
    __shared__ int sm[256];
    sm[t] = s;
    __syncthreads();
    for (int d = 1; d < 256; d <<= 1) {
        int u = (t >= d) ? sm[t - d] : 0;
        __syncthreads();
        sm[t] += u;
        __syncthreads();
    }
    int run = sm[t] - s;
    for (int k = 0; k < IPT; ++k) {
        int j = t * IPT + k;
        if (j < NBLK) {
            lbase[(size_t)b * NBLK + j] = run;
            run += v[k];
        }
    }
    if (t == 255) btot[b] = sm[255];
}

// ---- scan bucket totals -> regions ----
__global__ __launch_bounds__(NBKT) void k_gscan(const int* __restrict__ btot,
                                                int* __restrict__ gregion) {
    __shared__ int sm[NBKT];
    int t = threadIdx.x;
    int v = btot[t];
    sm[t] = v;
    __syncthreads();
    for (int d = 1; d < NBKT; d <<= 1) {
        int u = (t >= d) ? sm[t - d] : 0;
        __syncthreads();
        sm[t] += u;
        __syncthreads();
    }
    gregion[t] = sm[t] - v;
    if (t == NBKT - 1) gregion[NBKT] = sm[t];
}

// ---- bucket scatter: block-local LDS counting sort, runs at exact bases ----
// packed entry: (dst & 511) << 17 | src
__global__ __launch_bounds__(256) void k_scatter(const void* __restrict__ edges,
                                                 const int* __restrict__ gregion,
                                                 const int* __restrict__ lbase,
                                                 unsigned int* __restrict__ pairs,
                                                 int E, int NBLK) {
    __shared__ unsigned int raw[C1];
    __shared__ unsigned int srt[C1];
    __shared__ unsigned short bkt[C1];
    __shared__ unsigned short sbk[C1];
    __shared__ int hist[NBKT], scn[NBKT], gb[NBKT], cur[NBKT];
    const int* e32 = (const int*)edges;
    const long long* e64 = (const long long*)edges;
    const bool is64 = detect64(e32);
    const int t = threadIdx.x;
    const int base = blockIdx.x * C1;
    const int cnt = min(C1, E - base);
    hist[t] = 0;
    cur[t] = 0;
    __syncthreads();
    for (int j = t; j < cnt; j += 256) {
        int i = base + j;
        int src, dst;
        if (is64) {
            src = (int)e64[i];
            dst = (int)e64[(size_t)E + i];
        } else {
            src = e32[i];
            dst = e32[(size_t)E + i];
        }
        int b = dst >> BSH;
        raw[j] = (unsigned int)src | ((unsigned int)(dst & (NPBKT - 1)) << 17);
        bkt[j] = (unsigned short)b;
        atomicAdd(&hist[b], 1);
    }
    __syncthreads();
    int v = hist[t];
    scn[t] = v;
    __syncthreads();
    for (int d = 1; d < NBKT; d <<= 1) {
        int u = (t >= d) ? scn[t - d] : 0;
        __syncthreads();
        scn[t] += u;
        __syncthreads();
    }
    int ex = scn[t] - v;
    gb[t] = gregion[t] + lbase[(size_t)t * NBLK + blockIdx.x];
    __syncthreads();
    scn[t] = ex;
    __syncthreads();
    for (int j = t; j < cnt; j += 256) {
        int b = bkt[j];
        int r = atomicAdd(&cur[b], 1);
        int pos = scn[b] + r;
        srt[pos] = raw[j];
        sbk[pos] = (unsigned short)b;
    }
    __syncthreads();
    for (int j = t; j < cnt; j += 256) {
        int b = sbk[j];
        pairs[gb[b] + (j - scn[b])] = srt[j];
    }
}

// ---- node-level histogram per (bucket, subchunk); g-major layout ----
__global__ __launch_bounds__(256) void k_nhist(const unsigned int* __restrict__ pairs,
                                               const int* __restrict__ gregion,
                                               int* __restrict__ nh, int N) {
    const int b = blockIdx.x >> 3;
    const int g = blockIdx.x & 7;
    const int e0 = gregion[b], e1 = gregion[b + 1];
    const int L = e1 - e0;
    const int sb = e0 + ((L * g) >> 3);
    const int se = e0 + ((L * (g + 1)) >> 3);
    __shared__ int h[NPBKT];
    const int t = threadIdx.x;
    h[t] = 0;
    h[t + 256] = 0;
    __syncthreads();
    for (int e = sb + t; e < se; e += 256) atomicAdd(&h[pairs[e] >> 17], 1);
    __syncthreads();
    const int nbase = b << BSH;
    for (int l = t; l < NPBKT; l += 256) {
        int n = nbase + l;
        if (n < N) nh[(size_t)g * N + n] = h[l];
    }
}

// ---- per-node scan over subchunks + block scan of padded degrees ----
__global__ __launch_bounds__(256) void k_nscan(int* __restrict__ nh,
                                               float* __restrict__ dinv,
                                               int2* __restrict__ lc,
                                               int* __restrict__ btot2, int N) {
    const int t = threadIdx.x;
    const int n = blockIdx.x * 256 + t;
    int c = 0, p = 0;
    if (n < N) {
        int v[GSUB];
        int ex = 0;
#pragma unroll
        for (int g = 0; g < GSUB; ++g) v[g] = nh[(size_t)g * N + n];
#pragma unroll
        for (int g = 0; g < GSUB; ++g) {
            int vv = v[g];
            nh[(size_t)g * N + n] = ex;  // counts -> exclusive bases (in place)
            ex += vv;
        }
        c = ex;
        p = (c + 16) & ~15;  // self-loop + pad to multiple of 16
        dinv[n] = rsqrtf((float)(c + 1));
    }
    __shared__ int sm[256];
    sm[t] = p;
    __syncthreads();
    for (int d = 1; d < 256; d <<= 1) {
        int u = (t >= d) ? sm[t - d] : 0;
        __syncthreads();
        sm[t] += u;
        __syncthreads();
    }
    if (n < N) lc[n] = make_int2(sm[t] - p, c);  // (local offset, degree)
    if (t == 255) btot2[blockIdx.x] = sm[255];
}

// ---- scan per-block padded totals ----
__global__ __launch_bounds__(512) void k_gscan2(const int* __restrict__ btot2,
                                                int* __restrict__ bbase2, int nb) {
    __shared__ int sm[512];
    int t = threadIdx.x;
    int v = (t < nb) ? btot2[t] : 0;
    sm[t] = v;
    __syncthreads();
    for (int d = 1; d < 512; d <<= 1) {
        int u = (t >= d) ? sm[t - d] : 0;
        __syncthreads();
        sm[t] += u;
        __syncthreads();
    }
    if (t < nb) bbase2[t] = sm[t] - v;
}

// ---- finalize offsets, self-loop entries, sentinel pads ----
__global__ __launch_bounds__(256) void k_nfill(const int2* __restrict__ lc,
                                               const int* __restrict__ bbase2,
                                               int2* __restrict__ off2,
                                               int* __restrict__ srcs, int N) {
    const int n = blockIdx.x * 256 + threadIdx.x;
    if (n >= N) return;
    int2 l = lc[n];
    const int off = bbase2[blockIdx.x] + l.x;
    const int c = l.y;
    const int p = (c + 16) & ~15;
    off2[n] = make_int2(off, off + p);
    srcs[off] = n;  // self loop at slot 0
    for (int k = c + 1; k < p; ++k) srcs[off + k] = N;  // sentinel pad
}

// ---- node-level scatter per (bucket, subchunk) at precomputed bases ----
__global__ __launch_bounds__(256) void k_nscatter(const unsigned int* __restrict__ pairs,
                                                  const int* __restrict__ gregion,
                                                  const int* __restrict__ nh,
                                                  const int2* __restrict__ off2,
                                                  int* __restrict__ srcs, int N) {
    const int b = blockIdx.x >> 3;
    const int g = blockIdx.x & 7;
    const int e0 = gregion[b], e1 = gregion[b + 1];
    const int L = e1 - e0;
    const int sb = e0 + ((L * g) >> 3);
    const int se = e0 + ((L * (g + 1)) >> 3);
    __shared__ int cur[NPBKT];
    const int t = threadIdx.x;
    const int nbase = b << BSH;
    for (int l = t; l < NPBKT; l += 256) {
        int n = nbase + l;
        if (n < N) cur[l] = off2[n].x + 1 + nh[(size_t)g * N + n];
    }
    __syncthreads();
    for (int e = sb + t; e < se; e += 256) {
        unsigned int pr = pairs[e];
        int l = pr >> 17;
        int r = atomicAdd(&cur[l], 1);  // LDS only
        srcs[r] = (int)(pr & 0x1FFFFu);
    }
}

// ---- prep: u0[n] = fp16( dinv[n] * (x[n] @ W^T) ); zero sentinel rows ----
__global__ __launch_bounds__(256) void k_prep(const float* __restrict__ x,
                                              const float* __restrict__ dinv,
                                              const float* __restrict__ Wg,
                                              __half2* __restrict__ u0,
                                              __half2* __restrict__ u1, int N) {
    __shared__ float Wl[DIMOUT * NF];
    int t = threadIdx.x;
    if (t < DIMOUT * NF) Wl[t] = Wg[t];
    __syncthreads();
    if (blockIdx.x == 0 && t < 8) {
        u0[(size_t)N * 8 + t] = __floats2half2_rn(0.f, 0.f);
        u1[(size_t)N * 8 + t] = __floats2half2_rn(0.f, 0.f);
    }
    int n = blockIdx.x * 256 + t;
    if (n >= N) return;
    float xr[NF];
#pragma unroll
    for (int f = 0; f < NF; ++f) xr[f] = x[(size_t)n * NF + f];
    float dn = dinv[n];
#pragma unroll
    for (int q = 0; q < 8; ++q) {
        float r0 = 0.f, r1 = 0.f;
#pragma unroll
        for (int f = 0; f < NF; ++f) {
            r0 += xr[f] * Wl[(2 * q) * NF + f];
            r1 += xr[f] * Wl[(2 * q + 1) * NF + f];
        }
        u0[(size_t)n * 8 + q] = __floats2half2_rn(dn * r0, dn * r1);
    }
}

// ---- hop: wave per node, 16-way edge-parallel, 8B lanes, padded lists ----
template <int FINAL>
__global__ __launch_bounds__(256) void k_hop(const uint2* __restrict__ u8,
                                             const int* __restrict__ srcs,
                                             const int2* __restrict__ off2,
                                             const float* __restrict__ dinv,
                                             const float* __restrict__ bias,
                                             uint2* __restrict__ outh,
                                             float* __restrict__ outf, int N) {
    const int lane = threadIdx.x & 63;
    const int fp = lane & 3;
    const int ep = lane >> 2;
    const int n = blockIdx.x * 4 + (threadIdx.x >> 6);
    if (n >= N) return;
    const int2 oo = off2[n];
    const int beg = oo.x, end = oo.y;
    float ax = 0.f, ay = 0.f, az = 0.f, aw = 0.f;
    int e = beg + ep;
    for (; e + 16 < end; e += 32) {
        int s0 = srcs[e];
        int s1 = srcs[e + 16];
        uint2 q0 = u8[(size_t)s0 * 4 + fp];
        uint2 q1 = u8[(size_t)s1 * 4 + fp];
        float2 a0 = __half22float2(*(__half2*)&q0.x);
        float2 b0 = __half22float2(*(__half2*)&q0.y);
        float2 a1 = __half22float2(*(__half2*)&q1.x);
        float2 b1 = __half22float2(*(__half2*)&q1.y);
        ax += a0.x + a1.x;
        ay += a0.y + a1.y;
        az += b0.x + b1.x;
        aw += b0.y + b1.y;
    }
    if (e < end) {
        int s0 = srcs[e];
        uint2 q0 = u8[(size_t)s0 * 4 + fp];
        float2 a0 = __half22float2(*(__half2*)&q0.x);
        float2 b0 = __half22float2(*(__half2*)&q0.y);
        ax += a0.x;
        ay += a0.y;
        az += b0.x;
        aw += b0.y;
    }
#pragma unroll
    for (int d = 4; d <= 32; d <<= 1) {
        ax += __shfl_xor(ax, d);
        ay += __shfl_xor(ay, d);
        az += __shfl_xor(az, d);
        aw += __shfl_xor(aw, d);
    }
    if (ep != 0) return;
    float dn = dinv[n];
    if (!FINAL) {
        float s = dn * dn;
        __half2 h0 = __floats2half2_rn(s * ax, s * ay);
        __half2 h1 = __floats2half2_rn(s * az, s * aw);
        uint2 q;
        q.x = *(unsigned*)&h0;
        q.y = *(unsigned*)&h1;
        outh[(size_t)n * 4 + fp] = q;
    } else {
        float4 o;
        o.x = dn * ax + bias[4 * fp];
        o.y = dn * ay + bias[4 * fp + 1];
        o.z = dn * az + bias[4 * fp + 2];
        o.w = dn * aw + bias[4 * fp + 3];
        *(float4*)(outf + (size_t)n * DIMOUT + 4 * fp) = o;
    }
}

extern "C" void kernel_launch(void* const* d_in, const int* in_sizes, int n_in,
                              void* d_out, int out_size, void* d_ws, size_t ws_size,
                              hipStream_t stream) {
    const float* x = (const float*)d_in[0];
    const void* edges = d_in[1];
    const float* W = (const float*)d_in[2];
    const float* b = (const float*)d_in[3];
    float* out = (float*)d_out;

    const int N = in_sizes[0] / NF;  // 100000
    const int E = in_sizes[1] / 2;   // 3200000
    const int NBLK = (E + C1 - 1) / C1;
    const int NUSED = (N + NPBKT - 1) >> BSH;
    const int NBLK2 = (N + 255) / 256;

    char* ws = (char*)d_ws;
    size_t o = 0;
    auto alloc = [&](size_t bytes) -> void* {
        o = (o + 255) & ~(size_t)255;
        void* p = ws + o;
        o += bytes;
        return p;
    };
    int* lhistT = (int*)alloc((size_t)NBKT * NBLK * sizeof(int));
    int* lbase = (int*)alloc((size_t)NBKT * NBLK * sizeof(int));
    int* btot = (int*)alloc((size_t)NBKT * sizeof(int));
    int* gregion = (int*)alloc(((size_t)NBKT + 1) * sizeof(int));
    unsigned int* pairs = (unsigned int*)alloc((size_t)E * sizeof(unsigned int));
    int* srcs = (int*)alloc(((size_t)E + (size_t)16 * N + 256) * sizeof(int));
    int* nh = (int*)alloc((size_t)GSUB * N * sizeof(int));
    int2* lc = (int2*)alloc((size_t)N * sizeof(int2));
    int* btot2 = (int*)alloc((size_t)NBLK2 * sizeof(int));
    int* bbase2 = (int*)alloc((size_t)NBLK2 * sizeof(int));
    int2* off2 = (int2*)alloc((size_t)N * sizeof(int2));
    float* dinv = (float*)alloc((size_t)N * sizeof(float));
    __half* u0 = (__half*)alloc((size_t)(N + 1) * 16 * sizeof(__half));
    __half* u1 = (__half*)alloc((size_t)(N + 1) * 16 * sizeof(__half));
    (void)ws_size;
    (void)n_in;
    (void)out_size;

    k_lhist<<<NBLK, 256, 0, stream>>>(edges, lhistT, E, NBLK);
    k_cscan<<<NBKT, 256, 0, stream>>>(lhistT, lbase, btot, NBLK);
    k_gscan<<<1, NBKT, 0, stream>>>(btot, gregion);
    k_scatter<<<NBLK, 256, 0, stream>>>(edges, gregion, lbase, pairs, E, NBLK);
    k_nhist<<<NUSED * GSUB, 256, 0, stream>>>(pairs, gregion, nh, N);
    k_nscan<<<NBLK2, 256, 0, stream>>>(nh, dinv, lc, btot2, N);
    k_prep<<<NBLK2, 256, 0, stream>>>(x, dinv, W, (__half2*)u0, (__half2*)u1, N);
    k_gscan2<<<1, 512, 0, stream>>>(btot2, bbase2, NBLK2);
    k_nfill<<<NBLK2, 256, 0, stream>>>(lc, bbase2, off2, srcs, N);
    k_nscatter<<<NUSED * GSUB, 256, 0, stream>>>(pairs, gregion, nh, off2, srcs, N);

    int hopgrid = (N + 3) / 4;
    k_hop<0><<<hopgrid, 256, 0, stream>>>((const uint2*)u0, srcs, off2, dinv, nullptr,
                                          (uint2*)u1, nullptr, N);
    k_hop<1><<<hopgrid, 256, 0, stream>>>((const uint2*)u1, srcs, off2, dinv, b,
                                          nullptr, out, N);
}